// Round 3
// baseline (219.426 us; speedup 1.0000x reference)
//
#include <hip/hip_runtime.h>

#define NB 32
#define L2E 1.4426950408889634f

typedef float v2f __attribute__((ext_vector_type(2)));

static __device__ __forceinline__ float exp2f_fast(float x) {
#if __has_builtin(__builtin_amdgcn_exp2f)
    return __builtin_amdgcn_exp2f(x);
#else
    return __expf(x * 0.6931471805599453f);
#endif
}

#if __has_builtin(__builtin_elementwise_fma)
#define VFMA(a, b, c) __builtin_elementwise_fma(a, b, c)
#else
static __device__ inline v2f VFMA(v2f a, v2f b, v2f c) {
    v2f r; r.x = fmaf(a.x, b.x, c.x); r.y = fmaf(a.y, b.y, c.y); return r;
}
#endif

// Each thread owns one anchor (b,m) and ALL 32 bases over an N-segment.
// Key identity: gamma_k = 32/k^2 exactly (sigma_k = k/8), so
// gamma_k = 4*gamma_{2k}  =>  E_k = E_{2k}^4 (two squarings).
// Only k=17..32 (the divisibility-maximal "roots") need v_exp_f32;
// k=1..16 are derived by packed squarings: 16 exps/pair instead of 32.
__global__ __launch_bounds__(256) void gp_main(
    const float* __restrict__ f,
    const float* __restrict__ coords,
    const float* __restrict__ anchors,
    const float* __restrict__ gammas,
    const float* __restrict__ norms,
    float* __restrict__ ws,
    int B, int N, int M, int NSEG, int applyNorm)
{
    const int mtiles = M / 256;
    const int tile = blockIdx.x;          // over B * (M/256)
    const int seg  = blockIdx.y;          // N-segment
    const int b    = tile / mtiles;
    const int m    = (tile - b * mtiles) * 256 + threadIdx.x;
    const int bm   = b * M + m;

    const float ax = anchors[(size_t)bm * 3 + 0];
    const float ay = anchors[(size_t)bm * 3 + 1];
    const float az = anchors[(size_t)bm * 3 + 2];

    // -log2(e)*gamma_k for root bases k=17..32 only (uniform -> SGPRs)
    float negc[16];
#pragma unroll
    for (int j = 0; j < 16; ++j)
        negc[j] = -L2E * gammas[16 + j];

    v2f acc[16];
#pragma unroll
    for (int j = 0; j < 16; ++j) acc[j] = (v2f)(0.0f);

    const float* __restrict__ fb = f + (size_t)b * N;
    const float* __restrict__ cb = coords + (size_t)b * N * 3;

    const int n0 = seg * NSEG;
    const int n1 = (n0 + NSEG > N) ? N : (n0 + NSEG);

    // prefetch first point (wave-uniform -> scalar loads)
    float px = cb[(size_t)n0 * 3 + 0];
    float py = cb[(size_t)n0 * 3 + 1];
    float pz = cb[(size_t)n0 * 3 + 2];
    float fv = fb[n0];

    for (int n = n0; n < n1; ++n) {
        const float dx = ax - px, dy = ay - py, dz = az - pz;
        const float d2 = fmaf(dx, dx, fmaf(dy, dy, dz * dz));
        const float fcur = fv;

        // prefetch next point while we compute
        const int np = (n + 1 < n1) ? (n + 1) : n;
        px = cb[(size_t)np * 3 + 0];
        py = cb[(size_t)np * 3 + 1];
        pz = cb[(size_t)np * 3 + 2];
        fv = fb[np];

        float E[NB];  // E[k-1] = exp(-gamma_k * d2)
        // 16 roots via hardware exp2
#pragma unroll
        for (int j = 0; j < 16; ++j)
            E[16 + j] = exp2f_fast(d2 * negc[j]);

        // derived bases: E_k = (E_{2k}^2)^2, packed pairs (k, k-1), k=16..3
#pragma unroll
        for (int k = 16; k >= 3; k -= 2) {
            v2f t; t.x = E[2 * k - 1]; t.y = E[2 * k - 3];
            t = t * t;                 // v_pk_mul_f32
            t = t * t;
            E[k - 1] = t.x; E[k - 2] = t.y;
        }
        { const float t = E[3] * E[3]; E[1] = t * t; }   // E_2 = E_4^4
        { const float t = E[1] * E[1]; E[0] = t * t; }   // E_1 = E_2^4

        const v2f fvv = (v2f)(fcur);
#pragma unroll
        for (int j = 0; j < 16; ++j) {
            v2f e; e.x = E[2 * j]; e.y = E[2 * j + 1];
            acc[j] = VFMA(e, fvv, acc[j]);               // v_pk_fma_f32
        }
    }

    if (applyNorm) {
        float* __restrict__ w = ws + (size_t)bm * NB;
#pragma unroll
        for (int j = 0; j < 16; ++j) {
            w[2 * j + 0] = acc[j].x / norms[2 * j + 0];
            w[2 * j + 1] = acc[j].y / norms[2 * j + 1];
        }
    } else {
        v2f* __restrict__ w = (v2f*)(ws + ((size_t)seg * (B * M) + bm) * NB);
#pragma unroll
        for (int j = 0; j < 16; ++j) w[j] = acc[j];
    }
}

// Second pass: sum S partials (float4-vectorized) and apply 1/norm.
__global__ __launch_bounds__(256) void gp_reduce(
    const float4* __restrict__ ws,
    const float4* __restrict__ norms4,
    float4* __restrict__ out,
    int BM, int S)
{
    const int t = blockIdx.x * blockDim.x + threadIdx.x;   // over BM * NB/4
    if (t >= BM * (NB / 4)) return;
    const size_t stride = (size_t)BM * (NB / 4);
    float4 s = make_float4(0.f, 0.f, 0.f, 0.f);
    for (int i = 0; i < S; ++i) {
        const float4 v = ws[(size_t)i * stride + t];
        s.x += v.x; s.y += v.y; s.z += v.z; s.w += v.w;
    }
    const float4 nrm = norms4[t & (NB / 4 - 1)];
    s.x /= nrm.x; s.y /= nrm.y; s.z /= nrm.z; s.w /= nrm.w;
    out[t] = s;
}

extern "C" void kernel_launch(void* const* d_in, const int* in_sizes, int n_in,
                              void* d_out, int out_size, void* d_ws, size_t ws_size,
                              hipStream_t stream) {
    const float* f       = (const float*)d_in[0];
    const float* coords  = (const float*)d_in[1];
    const float* anchors = (const float*)d_in[2];
    const float* gammas  = (const float*)d_in[3];
    const float* norms   = (const float*)d_in[4];
    float* out = (float*)d_out;

    const int B = 2, N = 8192, M = 4096;
    const int BM = B * M;

    // Segments of N sized by workspace capacity (partials: S*BM*NB floats).
    int S = (int)(ws_size / ((size_t)BM * NB * sizeof(float)));
    if (S > 64) S = 64;
    int s2 = 1; while (s2 * 2 <= S) s2 *= 2;   // power of two dividing N
    S = (S >= 1) ? s2 : 0;

    if (S >= 2) {
        const int NSEG = N / S;
        dim3 grid(B * (M / 256), S);
        gp_main<<<grid, 256, 0, stream>>>(f, coords, anchors, gammas, norms,
                                          (float*)d_ws, B, N, M, NSEG, 0);
        const int total = BM * (NB / 4);
        gp_reduce<<<(total + 255) / 256, 256, 0, stream>>>(
            (const float4*)d_ws, (const float4*)norms, (float4*)out, BM, S);
    } else {
        dim3 grid(B * (M / 256), 1);
        gp_main<<<grid, 256, 0, stream>>>(f, coords, anchors, gammas, norms,
                                          out, B, N, M, N, 1);
    }
}

// Round 4
// 183.823 us; speedup vs baseline: 1.1937x; 1.1937x over previous
//
#include <hip/hip_runtime.h>

#define NB 32
#define L2E 1.4426950408889634f

typedef float v2f __attribute__((ext_vector_type(2)));

static __device__ __forceinline__ float exp2f_fast(float x) {
#if __has_builtin(__builtin_amdgcn_exp2f)
    return __builtin_amdgcn_exp2f(x);
#else
    return __expf(x * 0.6931471805599453f);
#endif
}

#if __has_builtin(__builtin_elementwise_fma)
#define VFMA(a, b, c) __builtin_elementwise_fma(a, b, c)
#else
static __device__ inline v2f VFMA(v2f a, v2f b, v2f c) {
    v2f r; r.x = fmaf(a.x, b.x, c.x); r.y = fmaf(a.y, b.y, c.y); return r;
}
#endif

// Storage position p (0..31) -> basis index k (1-based).
// Pairing chosen so every packed 4th-power derivation maps a whole v2f pair
// onto a whole v2f pair (E_k = E_{2k}^4, gamma_k = 32/k^2 exactly):
//   (E32,E24)^4=(E16,E12)  (E28,E20)^4=(E14,E10)  (E30,E22)^4=(E15,E11)
//   (E26,E18)^4=(E13,E9)   (E16,E12)^4=(E8,E6)    (E14,E10)^4=(E7,E5)
//   (E8,E6)^4=(E4,E3)      E2=E4^4, E1=E2^4 (scalar)
// => zero cross-register shuffles (R3's hidden v_mov tax).
static __device__ const int POS2K[NB] = {
    32,24, 28,20, 30,22, 26,18, 31,23, 29,21, 27,19, 25,17,
    16,12, 14,10, 15,11, 13,9,  8,6,   7,5,   4,3,   2,1 };

__global__ __launch_bounds__(256) void gp_main(
    const float* __restrict__ f,
    const float* __restrict__ coords,
    const float* __restrict__ anchors,
    const float* __restrict__ gammas,
    const float* __restrict__ norms,
    float* __restrict__ ws,
    int B, int N, int M, int NSEG, int applyNorm)
{
    const int mtiles = M / 256;
    const int tile = blockIdx.x;          // over B * (M/256)
    const int seg  = blockIdx.y;          // N-segment
    const int b    = tile / mtiles;
    const int m    = (tile - b * mtiles) * 256 + threadIdx.x;
    const int bm   = b * M + m;

    const float ax = anchors[(size_t)bm * 3 + 0];
    const float ay = anchors[(size_t)bm * 3 + 1];
    const float az = anchors[(size_t)bm * 3 + 2];

    // Root-basis constants -log2(e)*gamma_k for positions 0..15 (uniform).
    v2f c[8];
#pragma unroll
    for (int j = 0; j < 8; ++j) {
        c[j].x = -L2E * gammas[POS2K[2 * j + 0] - 1];
        c[j].y = -L2E * gammas[POS2K[2 * j + 1] - 1];
    }

    v2f acc[16];
#pragma unroll
    for (int j = 0; j < 16; ++j) acc[j] = (v2f)(0.0f);

    const float* __restrict__ fb = f + (size_t)b * N;
    const float* __restrict__ cb = coords + (size_t)b * N * 3;

    const int n0 = seg * NSEG;
    const int n1 = (n0 + NSEG > N) ? N : (n0 + NSEG);

    // prefetch first point (wave-uniform)
    float px = cb[(size_t)n0 * 3 + 0];
    float py = cb[(size_t)n0 * 3 + 1];
    float pz = cb[(size_t)n0 * 3 + 2];
    float fv = fb[n0];

    for (int n = n0; n < n1; ++n) {
        const float dx = ax - px, dy = ay - py, dz = az - pz;
        const float d2 = fmaf(dx, dx, fmaf(dy, dy, dz * dz));
        const float fcur = fv;

        const int np = (n + 1 < n1) ? (n + 1) : n;
        px = cb[(size_t)np * 3 + 0];
        py = cb[(size_t)np * 3 + 1];
        pz = cb[(size_t)np * 3 + 2];
        fv = fb[np];

        const v2f d2v = (v2f)(d2);

        // 8 root pairs: packed arg mul + 2 scalar exps each (arg dies fast)
        v2f e[8];
#pragma unroll
        for (int j = 0; j < 8; ++j) {
            const v2f a = d2v * c[j];          // v_pk_mul_f32
            e[j].x = exp2f_fast(a.x);          // v_exp_f32
            e[j].y = exp2f_fast(a.y);
        }

        // derived bases: whole-pair 4th powers, no shuffles
        v2f D0, D1, D2, D3, Q0, Q1, T0;
        { v2f t = e[0] * e[0]; D0 = t * t; }   // (E16,E12)
        { v2f t = e[1] * e[1]; D1 = t * t; }   // (E14,E10)
        { v2f t = e[2] * e[2]; D2 = t * t; }   // (E15,E11)
        { v2f t = e[3] * e[3]; D3 = t * t; }   // (E13,E9)
        { v2f t = D0 * D0;     Q0 = t * t; }   // (E8,E6)
        { v2f t = D1 * D1;     Q1 = t * t; }   // (E7,E5)
        { v2f t = Q0 * Q0;     T0 = t * t; }   // (E4,E3)
        const float u1 = T0.x * T0.x;
        const float E2 = u1 * u1;              // E2 = E4^4
        const float u2 = E2 * E2;
        const float E1 = u2 * u2;              // E1 = E2^4

        const v2f fv2 = (v2f)(fcur);
#pragma unroll
        for (int j = 0; j < 8; ++j)
            acc[j] = VFMA(e[j], fv2, acc[j]);  // v_pk_fma_f32
        acc[8]  = VFMA(D0, fv2, acc[8]);
        acc[9]  = VFMA(D1, fv2, acc[9]);
        acc[10] = VFMA(D2, fv2, acc[10]);
        acc[11] = VFMA(D3, fv2, acc[11]);
        acc[12] = VFMA(Q0, fv2, acc[12]);
        acc[13] = VFMA(Q1, fv2, acc[13]);
        acc[14] = VFMA(T0, fv2, acc[14]);
        acc[15].x = fmaf(E2, fcur, acc[15].x);
        acc[15].y = fmaf(E1, fcur, acc[15].y);
    }

    if (applyNorm) {
        // single-segment path: un-permute + normalize here
        float tmp[NB];
#pragma unroll
        for (int j = 0; j < 16; ++j) { tmp[2 * j] = acc[j].x; tmp[2 * j + 1] = acc[j].y; }
#pragma unroll
        for (int p = 0; p < NB; ++p) {
            const int k = POS2K[p];
            ws[(size_t)bm * NB + (k - 1)] = tmp[p] / norms[k - 1];
        }
    } else {
        // partials stay in permuted position order: contiguous v2f stores
        v2f* __restrict__ w = (v2f*)(ws + ((size_t)seg * (B * M) + bm) * NB);
#pragma unroll
        for (int j = 0; j < 16; ++j) w[j] = acc[j];
    }
}

// Second pass: sum S partials (float4 reads), un-permute, apply 1/norm.
__global__ __launch_bounds__(256) void gp_reduce(
    const float4* __restrict__ ws,
    const float* __restrict__ norms,
    float* __restrict__ out,
    int BM, int S)
{
    const int t = blockIdx.x * blockDim.x + threadIdx.x;   // over BM * NB/4
    if (t >= BM * (NB / 4)) return;
    const int bm = t >> 3;
    const int j  = t & 7;                                   // float4 group
    const size_t stride = (size_t)BM * (NB / 4);
    float4 s = make_float4(0.f, 0.f, 0.f, 0.f);
    for (int i = 0; i < S; ++i) {
        const float4 v = ws[(size_t)i * stride + t];
        s.x += v.x; s.y += v.y; s.z += v.z; s.w += v.w;
    }
    const float sv[4] = { s.x, s.y, s.z, s.w };
#pragma unroll
    for (int c = 0; c < 4; ++c) {
        const int k = POS2K[4 * j + c];
        out[(size_t)bm * NB + (k - 1)] = sv[c] / norms[k - 1];
    }
}

extern "C" void kernel_launch(void* const* d_in, const int* in_sizes, int n_in,
                              void* d_out, int out_size, void* d_ws, size_t ws_size,
                              hipStream_t stream) {
    const float* f       = (const float*)d_in[0];
    const float* coords  = (const float*)d_in[1];
    const float* anchors = (const float*)d_in[2];
    const float* gammas  = (const float*)d_in[3];
    const float* norms   = (const float*)d_in[4];
    float* out = (float*)d_out;

    const int B = 2, N = 8192, M = 4096;
    const int BM = B * M;

    // Segments of N sized by workspace capacity (partials: S*BM*NB floats).
    int S = (int)(ws_size / ((size_t)BM * NB * sizeof(float)));
    if (S > 64) S = 64;
    int s2 = 1; while (s2 * 2 <= S) s2 *= 2;   // power of two dividing N
    S = (S >= 1) ? s2 : 0;

    if (S >= 2) {
        const int NSEG = N / S;
        dim3 grid(B * (M / 256), S);
        gp_main<<<grid, 256, 0, stream>>>(f, coords, anchors, gammas, norms,
                                          (float*)d_ws, B, N, M, NSEG, 0);
        const int total = BM * (NB / 4);
        gp_reduce<<<(total + 255) / 256, 256, 0, stream>>>(
            (const float4*)d_ws, norms, out, BM, S);
    } else {
        dim3 grid(B * (M / 256), 1);
        gp_main<<<grid, 256, 0, stream>>>(f, coords, anchors, gammas, norms,
                                          out, B, N, M, N, 1);
    }
}

// Round 5
// 181.628 us; speedup vs baseline: 1.2081x; 1.0121x over previous
//
#include <hip/hip_runtime.h>

#define NB 32
#define L2E 1.4426950408889634f

typedef float v2f __attribute__((ext_vector_type(2)));

static __device__ __forceinline__ float exp2f_fast(float x) {
#if __has_builtin(__builtin_amdgcn_exp2f)
    return __builtin_amdgcn_exp2f(x);
#else
    return __expf(x * 0.6931471805599453f);
#endif
}

#if __has_builtin(__builtin_elementwise_fma)
#define VFMA(a, b, c) __builtin_elementwise_fma(a, b, c)
#else
static __device__ inline v2f VFMA(v2f a, v2f b, v2f c) {
    v2f r; r.x = fmaf(a.x, b.x, c.x); r.y = fmaf(a.y, b.y, c.y); return r;
}
#endif

// Storage position p (0..31) -> basis index k (1-based). Pairing chosen so
// every packed 4th-power derivation maps a whole v2f pair onto a whole v2f
// pair (E_k = E_{2k}^4 since gamma_k = 32/k^2 exactly): zero shuffles.
static __device__ const int POS2K[NB] = {
    32,24, 28,20, 30,22, 26,18, 31,23, 29,21, 27,19, 25,17,
    16,12, 14,10, 15,11, 13,9,  8,6,   7,5,   4,3,   2,1 };

__global__ __launch_bounds__(256, 4) void gp_main(
    const float* __restrict__ f,
    const float* __restrict__ coords,
    const float* __restrict__ anchors,
    const float* __restrict__ gammas,
    const float* __restrict__ norms,
    float* __restrict__ ws,
    int B, int N, int M, int NSEG, int applyNorm)
{
    const int mtiles = M / 256;
    const int tile = blockIdx.x;          // over B * (M/256)
    const int seg  = blockIdx.y;          // N-segment
    const int b    = tile / mtiles;
    const int m    = (tile - b * mtiles) * 256 + threadIdx.x;
    const int bm   = b * M + m;

    const float ax = anchors[(size_t)bm * 3 + 0];
    const float ay = anchors[(size_t)bm * 3 + 1];
    const float az = anchors[(size_t)bm * 3 + 2];

    // Root-basis constants -log2(e)*gamma_k for positions 0..15 (uniform->SGPR)
    v2f c[8];
#pragma unroll
    for (int j = 0; j < 8; ++j) {
        c[j].x = -L2E * gammas[POS2K[2 * j + 0] - 1];
        c[j].y = -L2E * gammas[POS2K[2 * j + 1] - 1];
    }

    v2f acc[16];
#pragma unroll
    for (int j = 0; j < 16; ++j) acc[j] = (v2f)(0.0f);

    const float* __restrict__ fb = f + (size_t)b * N;
    const float* __restrict__ cb = coords + (size_t)b * N * 3;

    const int n0 = seg * NSEG;            // NSEG is a multiple of 4
    const int groups = NSEG / 4;
    const float4* __restrict__ cb4 = (const float4*)(cb + (size_t)n0 * 3);
    const float4* __restrict__ fb4 = (const float4*)(fb + n0);

    // double-buffered wave-uniform batch: 4 points = 3 coord float4 + 1 f float4
    float4 C0 = cb4[0], C1 = cb4[1], C2 = cb4[2], F = fb4[0];

    for (int g = 0; g < groups; ++g) {
        const float4 c0 = C0, c1 = C1, c2 = C2, fq = F;
        const int gn = (g + 1 < groups) ? (g + 1) : g;
        C0 = cb4[3 * gn + 0];
        C1 = cb4[3 * gn + 1];
        C2 = cb4[3 * gn + 2];
        F  = fb4[gn];

        // 4 points' squared distances
        float d2q[4], fvq[4] = { fq.x, fq.y, fq.z, fq.w };
        { const float dx = ax - c0.x, dy = ay - c0.y, dz = az - c0.z;
          d2q[0] = fmaf(dx, dx, fmaf(dy, dy, dz * dz)); }
        { const float dx = ax - c0.w, dy = ay - c1.x, dz = az - c1.y;
          d2q[1] = fmaf(dx, dx, fmaf(dy, dy, dz * dz)); }
        { const float dx = ax - c1.z, dy = ay - c1.w, dz = az - c2.x;
          d2q[2] = fmaf(dx, dx, fmaf(dy, dy, dz * dz)); }
        { const float dx = ax - c2.y, dy = ay - c2.z, dz = az - c2.w;
          d2q[3] = fmaf(dx, dx, fmaf(dy, dy, dz * dz)); }

#pragma unroll
        for (int q = 0; q < 4; ++q) {
            const v2f d2v = (v2f)(d2q[q]);
            const v2f fv2 = (v2f)(fvq[q]);

            // 8 root pairs: packed arg mul + 2 exps each
            v2f e[8];
#pragma unroll
            for (int j = 0; j < 8; ++j) {
                const v2f a = d2v * c[j];
                e[j].x = exp2f_fast(a.x);
                e[j].y = exp2f_fast(a.y);
            }

            // derived bases: whole-pair 4th powers, no shuffles
            v2f D0, D1, D2, D3, Q0, Q1, T0;
            { v2f t = e[0] * e[0]; D0 = t * t; }   // (E16,E12)
            { v2f t = e[1] * e[1]; D1 = t * t; }   // (E14,E10)
            { v2f t = e[2] * e[2]; D2 = t * t; }   // (E15,E11)
            { v2f t = e[3] * e[3]; D3 = t * t; }   // (E13,E9)
            { v2f t = D0 * D0;     Q0 = t * t; }   // (E8,E6)
            { v2f t = D1 * D1;     Q1 = t * t; }   // (E7,E5)
            { v2f t = Q0 * Q0;     T0 = t * t; }   // (E4,E3)
            const float u1 = T0.x * T0.x;
            const float E2 = u1 * u1;              // E2 = E4^4
            const float u2 = E2 * E2;
            const float E1 = u2 * u2;              // E1 = E2^4

#pragma unroll
            for (int j = 0; j < 8; ++j)
                acc[j] = VFMA(e[j], fv2, acc[j]);
            acc[8]  = VFMA(D0, fv2, acc[8]);
            acc[9]  = VFMA(D1, fv2, acc[9]);
            acc[10] = VFMA(D2, fv2, acc[10]);
            acc[11] = VFMA(D3, fv2, acc[11]);
            acc[12] = VFMA(Q0, fv2, acc[12]);
            acc[13] = VFMA(Q1, fv2, acc[13]);
            acc[14] = VFMA(T0, fv2, acc[14]);
            acc[15].x = fmaf(E2, fvq[q], acc[15].x);
            acc[15].y = fmaf(E1, fvq[q], acc[15].y);
        }
    }

    if (applyNorm) {
        // single-segment path: un-permute + normalize here
        float tmp[NB];
#pragma unroll
        for (int j = 0; j < 16; ++j) { tmp[2 * j] = acc[j].x; tmp[2 * j + 1] = acc[j].y; }
#pragma unroll
        for (int p = 0; p < NB; ++p) {
            const int k = POS2K[p];
            ws[(size_t)bm * NB + (k - 1)] = tmp[p] / norms[k - 1];
        }
    } else {
        // partials stay in permuted position order: contiguous v2f stores
        v2f* __restrict__ w = (v2f*)(ws + ((size_t)seg * (B * M) + bm) * NB);
#pragma unroll
        for (int j = 0; j < 16; ++j) w[j] = acc[j];
    }
}

// Second pass: sum S partials (float4 reads), un-permute, apply 1/norm.
__global__ __launch_bounds__(256) void gp_reduce(
    const float4* __restrict__ ws,
    const float* __restrict__ norms,
    float* __restrict__ out,
    int BM, int S)
{
    const int t = blockIdx.x * blockDim.x + threadIdx.x;   // over BM * NB/4
    if (t >= BM * (NB / 4)) return;
    const int bm = t >> 3;
    const int j  = t & 7;                                   // float4 group
    const size_t stride = (size_t)BM * (NB / 4);
    float4 s = make_float4(0.f, 0.f, 0.f, 0.f);
    for (int i = 0; i < S; ++i) {
        const float4 v = ws[(size_t)i * stride + t];
        s.x += v.x; s.y += v.y; s.z += v.z; s.w += v.w;
    }
    const float sv[4] = { s.x, s.y, s.z, s.w };
#pragma unroll
    for (int c = 0; c < 4; ++c) {
        const int k = POS2K[4 * j + c];
        out[(size_t)bm * NB + (k - 1)] = sv[c] / norms[k - 1];
    }
}

extern "C" void kernel_launch(void* const* d_in, const int* in_sizes, int n_in,
                              void* d_out, int out_size, void* d_ws, size_t ws_size,
                              hipStream_t stream) {
    const float* f       = (const float*)d_in[0];
    const float* coords  = (const float*)d_in[1];
    const float* anchors = (const float*)d_in[2];
    const float* gammas  = (const float*)d_in[3];
    const float* norms   = (const float*)d_in[4];
    float* out = (float*)d_out;

    const int B = 2, N = 8192, M = 4096;
    const int BM = B * M;

    // Segments of N sized by workspace capacity (partials: S*BM*NB floats).
    int S = (int)(ws_size / ((size_t)BM * NB * sizeof(float)));
    if (S > 64) S = 64;
    int s2 = 1; while (s2 * 2 <= S) s2 *= 2;   // power of two dividing N
    S = (S >= 1) ? s2 : 0;

    if (S >= 2) {
        const int NSEG = N / S;
        dim3 grid(B * (M / 256), S);
        gp_main<<<grid, 256, 0, stream>>>(f, coords, anchors, gammas, norms,
                                          (float*)d_ws, B, N, M, NSEG, 0);
        const int total = BM * (NB / 4);
        gp_reduce<<<(total + 255) / 256, 256, 0, stream>>>(
            (const float4*)d_ws, norms, out, BM, S);
    } else {
        dim3 grid(B * (M / 256), 1);
        gp_main<<<grid, 256, 0, stream>>>(f, coords, anchors, gammas, norms,
                                          out, B, N, M, N, 1);
    }
}